// Round 16
// baseline (179.736 us; speedup 1.0000x reference)
//
#include <hip/hip_runtime.h>

typedef unsigned short ushort_t;
typedef __attribute__((ext_vector_type(8))) __bf16 bf16x8;
typedef __attribute__((ext_vector_type(4))) float f32x4;
typedef __attribute__((ext_vector_type(16))) float f32x16;
typedef __attribute__((ext_vector_type(4))) float float4v;
typedef __attribute__((ext_vector_type(8))) unsigned short ushort8v;
typedef __attribute__((ext_vector_type(4))) unsigned short ushort4v;
typedef __attribute__((ext_vector_type(4))) unsigned uint4v;

#define T_LEN 2048
#define D_DIM 1024
#define NHEAD 16
#define HDIM 64
#define BH 64                    // B * H
#define MROWS 8192               // B * T
#define PERQKV ((size_t)BH * T_LEN * HDIM)   // 8388608 elems

__device__ __forceinline__ ushort_t f2bf(float f) {
  unsigned u = __builtin_bit_cast(unsigned, f);
  u = (u + 0x7FFFu + ((u >> 16) & 1u)) >> 16;
  return (ushort_t)u;
}

// raw v_exp_f32 (2^x): libm exp2f adds ~12 edge-case instrs per call (r7 lesson)
__device__ __forceinline__ float fast_exp2(float x) {
  float r; asm("v_exp_f32 %0, %1" : "=v"(r) : "v"(x)); return r;
}
__device__ __forceinline__ float fast_rcp(float x) {
  float r; asm("v_rcp_f32 %0, %1" : "=v"(r) : "v"(x)); return r;
}

__device__ __forceinline__ void load_lds16(const ushort_t* g, ushort_t* l) {
  __builtin_amdgcn_global_load_lds((const __attribute__((address_space(1))) void*)g,
                                   (__attribute__((address_space(3))) void*)l, 16, 0, 0);
}

// ------- fused prep: x cvt (blocks 0..8191) + both W transposes (8192..12287) -------
__global__ __launch_bounds__(256) void k_prep(const float* __restrict__ x,
                                              const float* __restrict__ Wqkv,
                                              const float* __restrict__ Wproj,
                                              ushort_t* __restrict__ xb,
                                              ushort_t* __restrict__ WqT,
                                              ushort_t* __restrict__ WpT) {
  __shared__ ushort_t tile[32][33];
  int bid = blockIdx.x, tid = threadIdx.x;
  if (bid < 8192) {
    int i = bid * 256 + tid;
    float4v v = ((const float4v*)x)[i];
    ushort4v o;
    o[0] = f2bf(v[0]); o[1] = f2bf(v[1]); o[2] = f2bf(v[2]); o[3] = f2bf(v[3]);
    ((ushort4v*)xb)[i] = o;
    return;
  }
  bid -= 8192;                       // 4096 transpose blocks: bx in [0,128), by in [0,32)
  int bx = bid & 127, by = bid >> 7;
  const float* W; ushort_t* Wt; int C;
  if (bx < 96) { W = Wqkv; Wt = WqT; C = 3072; }
  else         { W = Wproj; Wt = WpT; C = 1024; bx -= 96; }
  const int R = 1024;
  int tx = tid & 31, ty = tid >> 5;
  int r0 = by << 5, c0 = bx << 5;
#pragma unroll
  for (int i = 0; i < 4; ++i) {
    int r = ty + i * 8;
    tile[r][tx] = f2bf(W[(size_t)(r0 + r) * C + c0 + tx]);
  }
  __syncthreads();
#pragma unroll
  for (int i = 0; i < 4; ++i) {
    int r = ty + i * 8;
    Wt[(size_t)(c0 + r) * R + r0 + tx] = tile[tx][r];
  }
}

// ---- GEMM (QKV): 128x128 tile, BK=64, 2-barrier, 256 thr = 4 waves (2x2) ----
// r16: BK 32->64 halves barrier-pairs (drain amortized over 32 MFMA) while
// LDS stays 32KB -> ~5 blocks/CU TLP keeps the drain covered (m132's BK=128
// regression was the 64KB->2-block occupancy cliff, avoided here).
// Granule-XOR swizzle identical to k_gemm3 (measured 0 bank conflicts).
template <int N, int K, int EPI>
__global__ __launch_bounds__(256) void k_gemm64(const ushort_t* __restrict__ A,
                                                const ushort_t* __restrict__ Bt,
                                                ushort_t* __restrict__ O16,
                                                float* __restrict__ O32) {
  __shared__ __align__(16) ushort_t Atile[128 * 64];   // 16KB
  __shared__ __align__(16) ushort_t Btile[128 * 64];   // 16KB
  const int tid = threadIdx.x;
  const int lane = tid & 63, w = tid >> 6;
  const int g = lane >> 4, c = lane & 15;
  const int wm = w >> 1, wn = w & 1;
  const int m0 = blockIdx.y * 128, n0 = blockIdx.x * 128;

  f32x4 acc[4][4];
#pragma unroll
  for (int i = 0; i < 4; ++i)
#pragma unroll
    for (int j = 0; j < 4; ++j) acc[i][j] = (f32x4){0.f, 0.f, 0.f, 0.f};

  for (int k0 = 0; k0 < K; k0 += 64) {
    __syncthreads();
    // stage: 128 rows x 8 granules = 1024 granule-slots; 4 per thread
#pragma unroll
    for (int l = 0; l < 4; ++l) {
      int flat = l * 256 + tid;
      int row = flat >> 3, sl = flat & 7;
      int gsl = sl ^ (row & 7);                 // source-swizzle (rule #21)
      load_lds16(A + (size_t)(m0 + row) * K + k0 + gsl * 8, &Atile[(l * 256 + w * 64) * 8]);
      load_lds16(Bt + (size_t)(n0 + row) * K + k0 + gsl * 8, &Btile[(l * 256 + w * 64) * 8]);
    }
    __syncthreads();

#pragma unroll
    for (int kk = 0; kk < 2; ++kk) {
      bf16x8 af[4], bfr[4];
#pragma unroll
      for (int mi = 0; mi < 4; ++mi) {
        int row = wm * 64 + mi * 16 + c;
        af[mi] = *(const bf16x8*)&Atile[row * 64 + (((kk * 4 + g) ^ (row & 7)) << 3)];
      }
#pragma unroll
      for (int ni = 0; ni < 4; ++ni) {
        int row = wn * 64 + ni * 16 + c;
        bfr[ni] = *(const bf16x8*)&Btile[row * 64 + (((kk * 4 + g) ^ (row & 7)) << 3)];
      }
      __builtin_amdgcn_s_setprio(1);
#pragma unroll
      for (int mi = 0; mi < 4; ++mi)
#pragma unroll
        for (int ni = 0; ni < 4; ++ni)
          acc[mi][ni] = __builtin_amdgcn_mfma_f32_16x16x32_bf16(af[mi], bfr[ni],
                                                                acc[mi][ni], 0, 0, 0);
      __builtin_amdgcn_s_setprio(0);
    }
  }

#pragma unroll
  for (int mi = 0; mi < 4; ++mi)
#pragma unroll
    for (int ni = 0; ni < 4; ++ni) {
      int n = n0 + wn * 64 + ni * 16 + c;
#pragma unroll
      for (int j = 0; j < 4; ++j) {
        int m = m0 + wm * 64 + mi * 16 + g * 4 + j;
        float v = acc[mi][ni][j];
        if constexpr (EPI == 0) {
          int which = n >> 10, hn = n & 1023;
          int h = hn >> 6, d = hn & 63;
          int b = m >> 11, t = m & 2047;
          if (which == 0) v *= 0.18033688f;   // 1/sqrt(64) * log2(e) folded into Q
          O16[(size_t)which * PERQKV +
              (((size_t)(b * NHEAD + h) * T_LEN + t) * HDIM + d)] = f2bf(v);
        } else {
          O32[(size_t)m * N + n] = v;
        }
      }
    }
}

// ---- GEMM v3 (T4 counted-vmcnt): GEMM2 only (256 blocks = 1 round; B L2-fit).
// Measured ~15us (1147 TF). At GEMM1's multi-round shape it is latency-exposed
// at 1 block/CU (r12: 84.8us; r15 with L2 fix: 77.5us) -- do NOT use there.
template <int NB_TILES, int EPI>   // NB_TILES = N/256
__global__ __launch_bounds__(512, 2) void k_gemm3(const ushort_t* __restrict__ A,
                                                  const ushort_t* __restrict__ Bt,
                                                  ushort_t* __restrict__ O16,
                                                  float* __restrict__ O32) {
  __shared__ __align__(16) ushort_t As[3][128 * 64];   // 3 x 16KB
  __shared__ __align__(16) ushort_t Bs[3][256 * 64];   // 3 x 32KB
  const int tid = threadIdx.x, lane = tid & 63, w = tid >> 6;
  const int g = lane >> 4, c = lane & 15;
  const int wm = w & 1, wn = w >> 1;                   // 2M x 4N
  const int nblk = 64 * NB_TILES;
  const int chunk = nblk >> 3;                         // blocks per XCD
  const int bid = blockIdx.x;
  const int logical = (bid & 7) * chunk + (bid >> 3);  // T1 XCD swizzle
  const int mb = logical & 63, nb = logical >> 6;
  const int m0 = mb * 128, n0 = nb * 256;

  const int srow = lane >> 3, sgran = lane & 7;

  auto stage = [&](int t, int buf) {
    const int k0 = t * 64;
#pragma unroll
    for (int l = 0; l < 2; ++l) {
      int r = w * 16 + l * 8 + srow;
      load_lds16(A + (size_t)(m0 + r) * 1024 + k0 + ((sgran ^ (r & 7)) << 3),
                 &As[buf][(w * 16 + l * 8) * 64]);
    }
#pragma unroll
    for (int l = 0; l < 4; ++l) {
      int r = w * 32 + l * 8 + srow;
      load_lds16(Bt + (size_t)(n0 + r) * 1024 + k0 + ((sgran ^ (r & 7)) << 3),
                 &Bs[buf][(w * 32 + l * 8) * 64]);
    }
  };

  f32x4 acc[4][4];
#pragma unroll
  for (int i = 0; i < 4; ++i)
#pragma unroll
    for (int j = 0; j < 4; ++j) acc[i][j] = (f32x4){0.f, 0.f, 0.f, 0.f};

  stage(0, 0);
  stage(1, 1);

  for (int t = 0; t < 16; ++t) {
    if (t < 15) asm volatile("s_waitcnt vmcnt(6)" ::: "memory");
    else        asm volatile("s_waitcnt vmcnt(0)" ::: "memory");
    __builtin_amdgcn_s_barrier();
    __builtin_amdgcn_sched_barrier(0);

    if (t + 2 < 16) stage(t + 2, (t + 2) % 3);

    const int cur = t % 3;
    const ushort_t* abuf = &As[cur][0];
    const ushort_t* bbuf = &Bs[cur][0];
#pragma unroll
    for (int kk = 0; kk < 2; ++kk) {
      bf16x8 af[4], bq[4];
#pragma unroll
      for (int fr = 0; fr < 4; ++fr) {
        int r = wm * 64 + fr * 16 + c;
        af[fr] = *(const bf16x8*)&abuf[r * 64 + (((kk * 4 + g) ^ (r & 7)) << 3)];
      }
#pragma unroll
      for (int fc = 0; fc < 4; ++fc) {
        int r = wn * 64 + fc * 16 + c;
        bq[fc] = *(const bf16x8*)&bbuf[r * 64 + (((kk * 4 + g) ^ (r & 7)) << 3)];
      }
      __builtin_amdgcn_s_setprio(1);
#pragma unroll
      for (int fr = 0; fr < 4; ++fr)
#pragma unroll
        for (int fc = 0; fc < 4; ++fc)
          acc[fr][fc] = __builtin_amdgcn_mfma_f32_16x16x32_bf16(af[fr], bq[fc],
                                                                acc[fr][fc], 0, 0, 0);
      __builtin_amdgcn_s_setprio(0);
    }
  }

  // epilogue
#pragma unroll
  for (int fr = 0; fr < 4; ++fr)
#pragma unroll
    for (int fc = 0; fc < 4; ++fc) {
      int n = n0 + wn * 64 + fc * 16 + c;
#pragma unroll
      for (int j = 0; j < 4; ++j) {
        int m = m0 + wm * 64 + fr * 16 + g * 4 + j;
        float v = acc[fr][fc][j];
        if constexpr (EPI == 0) {
          int which = n >> 10, hn = n & 1023;
          int h = hn >> 6, d = hn & 63;
          int b = m >> 11, tt = m & 2047;
          if (which == 0) v *= 0.18033688f;
          O16[(size_t)which * PERQKV +
              (((size_t)(b * NHEAD + h) * T_LEN + tt) * HDIM + d)] = f2bf(v);
        } else {
          O32[(size_t)m * (64 * NB_TILES * 4) + n] = v;   // N = NB_TILES*256
        }
      }
    }
}

// ---------------- flash attention v10: paired q-tiles + VALU diet ----------------
// (unchanged from r14: 75.7us)
__global__ __launch_bounds__(128, 2) void k_attn(const ushort_t* __restrict__ Q,
                                                 const ushort_t* __restrict__ Kv,
                                                 const ushort_t* __restrict__ Vv,
                                                 ushort_t* __restrict__ Y) {
  __shared__ __align__(16) ushort_t Kt[2][64 * 64];   // [k][d], granule swz ^(k&7)
  __shared__ __align__(16) ushort_t Vt[2][64 * 64];   // [d][k], granule swz ^(d&7)

  const int bid = blockIdx.x;                          // 0..1023
  const int bh = (bid & 7) * 8 + ((bid >> 3) & 7);     // 8 bh per XCD (L2-fit)
  const int pairidx = bid >> 6;                        // 0..15
  const int pA = 31 - pairidx, pB = pairidx;
  const int nktA = pA + 1;
  const int total = nktA + pB + 1;                     // 34 for every block

  const int tid = threadIdx.x, lane = tid & 63, w = tid >> 6;  // w in {0,1}
  const int hi = lane >> 5, lc = lane & 31;
  const size_t base = (size_t)bh * (T_LEN * HDIM);

  f32x16 z16;
#pragma unroll
  for (int i = 0; i < 16; ++i) z16[i] = 0.f;
  uint4v ow; ow[0] = ow[1] = ow[2] = ow[3] = 0x3F803F80u;   // 8x bf16 1.0
  const bf16x8 onesf = __builtin_bit_cast(bf16x8, ow);

  int q32 = pA * 64 + w * 32;
  bf16x8 qf[4];
#pragma unroll
  for (int st = 0; st < 4; ++st)
    qf[st] = *(const bf16x8*)(Q + base + (size_t)(q32 + lc) * HDIM + st * 16 + hi * 8);

  f32x16 o0, o1, ol;
#pragma unroll
  for (int i = 0; i < 16; ++i) { o0[i] = 0.f; o1[i] = 0.f; ol[i] = 0.f; }
  float mrun = 0.f;   // scores bounded ~7 << THR=11

  const int ksl = tid & 7, krow0 = tid >> 3;
  const int kpair = tid & 31, vk0 = 2 * kpair, vd0 = (tid >> 5) * 8;

  bf16x8 kreg[4];
  ushort8v vreg[4];
  auto stage_issue = [&](int kt) {
    const ushort_t* kb = Kv + base + (size_t)kt * 64 * HDIM;
    const ushort_t* vb = Vv + base + (size_t)kt * 64 * HDIM;
    vreg[0] = *(const ushort8v*)(vb + (size_t)vk0 * HDIM + vd0);
    vreg[1] = *(const ushort8v*)(vb + (size_t)(vk0 + 1) * HDIM + vd0);
    vreg[2] = *(const ushort8v*)(vb + (size_t)vk0 * HDIM + vd0 + 32);
    vreg[3] = *(const ushort8v*)(vb + (size_t)(vk0 + 1) * HDIM + vd0 + 32);
#pragma unroll
    for (int m = 0; m < 4; ++m)
      kreg[m] = *(const bf16x8*)(kb + (size_t)(krow0 + 16 * m) * HDIM + ksl * 8);
  };
  auto stage_write = [&](int buf) {
#pragma unroll
    for (int m = 0; m < 4; ++m) {
      int r = krow0 + 16 * m;
      *(bf16x8*)&Kt[buf][r * 64 + ((ksl ^ (r & 7)) << 3)] = kreg[m];
    }
    uint4v a0 = __builtin_bit_cast(uint4v, vreg[0]);
    uint4v a1 = __builtin_bit_cast(uint4v, vreg[1]);
    uint4v a2 = __builtin_bit_cast(uint4v, vreg[2]);
    uint4v a3 = __builtin_bit_cast(uint4v, vreg[3]);
#pragma unroll
    for (int i = 0; i < 4; ++i) {
      unsigned lo, hi2, lo2, hi3;
      asm("v_perm_b32 %0, %1, %2, %3" : "=v"(lo)  : "v"(a1[i]), "v"(a0[i]), "s"(0x05040100u));
      asm("v_perm_b32 %0, %1, %2, %3" : "=v"(hi2) : "v"(a1[i]), "v"(a0[i]), "s"(0x07060302u));
      asm("v_perm_b32 %0, %1, %2, %3" : "=v"(lo2) : "v"(a3[i]), "v"(a2[i]), "s"(0x05040100u));
      asm("v_perm_b32 %0, %1, %2, %3" : "=v"(hi3) : "v"(a3[i]), "v"(a2[i]), "s"(0x07060302u));
      int rd = vd0 + 2 * i;
      *(unsigned*)&Vt[buf][rd * 64 + (((kpair >> 2) ^ (rd & 7)) << 3) + 2 * (kpair & 3)] = lo;
      int rd1 = rd + 1;
      *(unsigned*)&Vt[buf][rd1 * 64 + (((kpair >> 2) ^ (rd1 & 7)) << 3) + 2 * (kpair & 3)] = hi2;
      int rd2 = rd + 32;
      *(unsigned*)&Vt[buf][rd2 * 64 + (((kpair >> 2) ^ (rd2 & 7)) << 3) + 2 * (kpair & 3)] = lo2;
      int rd3 = rd + 33;
      *(unsigned*)&Vt[buf][rd3 * 64 + (((kpair >> 2) ^ (rd3 & 7)) << 3) + 2 * (kpair & 3)] = hi3;
    }
  };

  const int b_ = bh >> 4, h_ = bh & 15;
  auto epilogue = [&]() {
#pragma unroll
    for (int r = 0; r < 16; ++r) {
      int cr = (r & 3) + 8 * (r >> 2) + 4 * hi;
      float iv = fast_rcp(ol[r]);
      size_t m = (size_t)b_ * T_LEN + q32 + cr;
      Y[m * D_DIM + h_ * HDIM + lc]      = f2bf(o0[r] * iv);
      Y[m * D_DIM + h_ * HDIM + 32 + lc] = f2bf(o1[r] * iv);
    }
  };

  stage_issue(0); stage_write(0);
  stage_issue(1);
  __syncthreads();

  for (int it = 0; it < total; ++it) {
    if (it == nktA) {
      epilogue();
      q32 = pB * 64 + w * 32;
#pragma unroll
      for (int st = 0; st < 4; ++st)
        qf[st] = *(const bf16x8*)(Q + base + (size_t)(q32 + lc) * HDIM + st * 16 + hi * 8);
#pragma unroll
      for (int i = 0; i < 16; ++i) { o0[i] = 0.f; o1[i] = 0.f; ol[i] = 0.f; }
      mrun = 0.f;
    }
    const int kt = (it < nktA) ? it : it - nktA;
    const int cur = it & 1;
    const ushort_t* kbuf = &Kt[cur][0];
    const ushort_t* vbuf = &Vt[cur][0];

    __builtin_amdgcn_s_setprio(1);
    bf16x8 kf0 = *(const bf16x8*)&kbuf[lc * 64 + ((hi ^ (lc & 7)) << 3)];
    f32x16 s0 = __builtin_amdgcn_mfma_f32_32x32x16_bf16(kf0, qf[0], z16, 0, 0, 0);
#pragma unroll
    for (int st = 1; st < 4; ++st) {
      bf16x8 kf = *(const bf16x8*)&kbuf[lc * 64 + (((2 * st + hi) ^ (lc & 7)) << 3)];
      s0 = __builtin_amdgcn_mfma_f32_32x32x16_bf16(kf, qf[st], s0, 0, 0, 0);
    }
    bf16x8 kg0 = *(const bf16x8*)&kbuf[(32 + lc) * 64 + ((hi ^ (lc & 7)) << 3)];
    f32x16 s1 = __builtin_amdgcn_mfma_f32_32x32x16_bf16(kg0, qf[0], z16, 0, 0, 0);
#pragma unroll
    for (int st = 1; st < 4; ++st) {
      bf16x8 kg = *(const bf16x8*)&kbuf[(32 + lc) * 64 + (((2 * st + hi) ^ (lc & 7)) << 3)];
      s1 = __builtin_amdgcn_mfma_f32_32x32x16_bf16(kg, qf[st], s1, 0, 0, 0);
    }
    __builtin_amdgcn_s_setprio(0);

    if (kt * 64 + 63 > q32) {
      const int q = q32 + lc;
#pragma unroll
      for (int r = 0; r < 16; ++r) {
        int cr = (r & 3) + 8 * (r >> 2) + 4 * hi;
        if (kt * 64 + cr > q)      s0[r] = -3.0e38f;
        if (kt * 64 + 32 + cr > q) s1[r] = -3.0e38f;
      }
    }

    float tm[8];
#pragma unroll
    for (int i = 0; i < 8; ++i) tm[i] = fmaxf(fmaxf(s0[i], s0[i + 8]), fmaxf(s1[i], s1[i + 8]));
#pragma unroll
    for (int i = 0; i < 4; ++i) tm[i] = fmaxf(tm[i], tm[i + 4]);
    float tmax = fmaxf(fmaxf(tm[0], tm[1]), fmaxf(tm[2], tm[3]));
    tmax = fmaxf(tmax, __shfl_xor(tmax, 32));

    if (!__all(tmax <= mrun + 11.0f)) {
      float mnew = fmaxf(mrun, tmax);
      float sc = fast_exp2(mrun - mnew);
      mrun = mnew;
#pragma unroll
      for (int r = 0; r < 16; ++r) {
        int cr = (r & 3) + 8 * (r >> 2) + 4 * hi;
        float scr = __shfl(sc, cr);
        o0[r] *= scr; o1[r] *= scr; ol[r] *= scr;
      }
    }

#pragma unroll
    for (int r = 0; r < 16; ++r) s0[r] = fast_exp2(s0[r] - mrun);
#pragma unroll
    for (int r = 0; r < 16; ++r) s1[r] = fast_exp2(s1[r] - mrun);

    unsigned wv[16];
#pragma unroll
    for (int i = 0; i < 8; ++i) {
      asm("v_cvt_pk_bf16_f32 %0, %1, %2" : "=v"(wv[i])     : "v"(s0[2 * i]), "v"(s0[2 * i + 1]));
      asm("v_cvt_pk_bf16_f32 %0, %1, %2" : "=v"(wv[8 + i]) : "v"(s1[2 * i]), "v"(s1[2 * i + 1]));
    }
    bf16x8 pf[4];
#pragma unroll
    for (int g4 = 0; g4 < 4; ++g4) {
      unsigned a0 = wv[4 * g4], a1 = wv[4 * g4 + 1];
      unsigned a2 = wv[4 * g4 + 2], a3 = wv[4 * g4 + 3];
      asm("v_permlane32_swap_b32 %0, %1" : "+v"(a0), "+v"(a2));
      asm("v_permlane32_swap_b32 %0, %1" : "+v"(a1), "+v"(a3));
      uint4v fw; fw[0] = a0; fw[1] = a1; fw[2] = a2; fw[3] = a3;
      pf[g4] = __builtin_bit_cast(bf16x8, fw);
    }

    __builtin_amdgcn_s_setprio(1);
#pragma unroll
    for (int km = 0; km < 4; ++km) {
      int gsl = ((2 * km + hi) ^ (lc & 7)) << 3;
      bf16x8 vb0 = *(const bf16x8*)&vbuf[lc * 64 + gsl];
      bf16x8 vb1 = *(const bf16x8*)&vbuf[(32 + lc) * 64 + gsl];
      o0 = __builtin_amdgcn_mfma_f32_32x32x16_bf16(pf[km], vb0, o0, 0, 0, 0);
      o1 = __builtin_amdgcn_mfma_f32_32x32x16_bf16(pf[km], vb1, o1, 0, 0, 0);
      ol = __builtin_amdgcn_mfma_f32_32x32x16_bf16(pf[km], onesf, ol, 0, 0, 0);
    }
    __builtin_amdgcn_s_setprio(0);

    if (it + 1 < total) stage_write((it + 1) & 1);
    if (it + 2 < total) {
      int itn = it + 2;
      stage_issue((itn < nktA) ? itn : itn - nktA);
    }
    __syncthreads();
  }

  epilogue();
}

extern "C" void kernel_launch(void* const* d_in, const int* in_sizes, int n_in,
                              void* d_out, int out_size, void* d_ws, size_t ws_size,
                              hipStream_t stream) {
  const float* x     = (const float*)d_in[0];
  const float* Wqkv  = (const float*)d_in[1];
  const float* Wproj = (const float*)d_in[2];
  float* out = (float*)d_out;
  ushort_t* ws = (ushort_t*)d_ws;

  ushort_t* Xb  = ws;
  ushort_t* WqT = Xb  + (size_t)MROWS * D_DIM;        // 8192*1024
  ushort_t* WpT = WqT + (size_t)3 * D_DIM * D_DIM;    // 3072*1024
  ushort_t* Qb  = WpT + (size_t)D_DIM * D_DIM;        // 1024*1024
  ushort_t* Kb  = Qb + PERQKV;
  ushort_t* Vb  = Kb + PERQKV;
  ushort_t* Yb  = Vb + PERQKV;

  k_prep<<<8192 + 4096, 256, 0, stream>>>(x, Wqkv, Wproj, Xb, WqT, WpT);
  k_gemm64<3 * D_DIM, D_DIM, 0><<<dim3(3 * D_DIM / 128, MROWS / 128), 256, 0, stream>>>(Xb, WqT, Qb, nullptr);
  k_attn<<<1024, 128, 0, stream>>>(Qb, Kb, Vb, Yb);
  k_gemm3<4, 1><<<256, 512, 0, stream>>>(Yb, WpT, nullptr, out);
}

// Round 17
// 174.455 us; speedup vs baseline: 1.0303x; 1.0303x over previous
//
#include <hip/hip_runtime.h>

typedef unsigned short ushort_t;
typedef __attribute__((ext_vector_type(8))) __bf16 bf16x8;
typedef __attribute__((ext_vector_type(4))) float f32x4;
typedef __attribute__((ext_vector_type(16))) float f32x16;
typedef __attribute__((ext_vector_type(4))) float float4v;
typedef __attribute__((ext_vector_type(8))) unsigned short ushort8v;
typedef __attribute__((ext_vector_type(4))) unsigned short ushort4v;
typedef __attribute__((ext_vector_type(4))) unsigned uint4v;

#define T_LEN 2048
#define D_DIM 1024
#define NHEAD 16
#define HDIM 64
#define BH 64                    // B * H
#define MROWS 8192               // B * T
#define PERQKV ((size_t)BH * T_LEN * HDIM)   // 8388608 elems

__device__ __forceinline__ ushort_t f2bf(float f) {
  unsigned u = __builtin_bit_cast(unsigned, f);
  u = (u + 0x7FFFu + ((u >> 16) & 1u)) >> 16;
  return (ushort_t)u;
}

// raw v_exp_f32 (2^x): libm exp2f adds ~12 edge-case instrs per call (r7 lesson)
__device__ __forceinline__ float fast_exp2(float x) {
  float r; asm("v_exp_f32 %0, %1" : "=v"(r) : "v"(x)); return r;
}
__device__ __forceinline__ float fast_rcp(float x) {
  float r; asm("v_rcp_f32 %0, %1" : "=v"(r) : "v"(x)); return r;
}

__device__ __forceinline__ void load_lds16(const ushort_t* g, ushort_t* l) {
  __builtin_amdgcn_global_load_lds((const __attribute__((address_space(1))) void*)g,
                                   (__attribute__((address_space(3))) void*)l, 16, 0, 0);
}

// ------- fused prep: x cvt (blocks 0..8191) + both W transposes (8192..12287) -------
__global__ __launch_bounds__(256) void k_prep(const float* __restrict__ x,
                                              const float* __restrict__ Wqkv,
                                              const float* __restrict__ Wproj,
                                              ushort_t* __restrict__ xb,
                                              ushort_t* __restrict__ WqT,
                                              ushort_t* __restrict__ WpT) {
  __shared__ ushort_t tile[32][33];
  int bid = blockIdx.x, tid = threadIdx.x;
  if (bid < 8192) {
    int i = bid * 256 + tid;
    float4v v = ((const float4v*)x)[i];
    ushort4v o;
    o[0] = f2bf(v[0]); o[1] = f2bf(v[1]); o[2] = f2bf(v[2]); o[3] = f2bf(v[3]);
    ((ushort4v*)xb)[i] = o;
    return;
  }
  bid -= 8192;                       // 4096 transpose blocks: bx in [0,128), by in [0,32)
  int bx = bid & 127, by = bid >> 7;
  const float* W; ushort_t* Wt; int C;
  if (bx < 96) { W = Wqkv; Wt = WqT; C = 3072; }
  else         { W = Wproj; Wt = WpT; C = 1024; bx -= 96; }
  const int R = 1024;
  int tx = tid & 31, ty = tid >> 5;
  int r0 = by << 5, c0 = bx << 5;
#pragma unroll
  for (int i = 0; i < 4; ++i) {
    int r = ty + i * 8;
    tile[r][tx] = f2bf(W[(size_t)(r0 + r) * C + c0 + tx]);
  }
  __syncthreads();
#pragma unroll
  for (int i = 0; i < 4; ++i) {
    int r = ty + i * 8;
    Wt[(size_t)(c0 + r) * R + r0 + tx] = tile[tx][r];
  }
}

// ---------------- GEMM (QKV): 128x128, BK=32, 2-barrier, 4 blocks/CU ----------------
// Proven ~60us for GEMM1 (best of: BK=32/60, BK=64/63, counted-vmcnt/77-85,
// 256x192/60). The vmcnt(0) barrier drain is covered by cross-block TLP.
template <int N, int K, int EPI>
__global__ __launch_bounds__(256) void k_gemm(const ushort_t* __restrict__ A,
                                              const ushort_t* __restrict__ Bt,
                                              ushort_t* __restrict__ O16,
                                              float* __restrict__ O32) {
  __shared__ __align__(16) ushort_t Atile[128 * 32];
  __shared__ __align__(16) ushort_t Btile[128 * 32];
  const int tid = threadIdx.x;
  const int lane = tid & 63, w = tid >> 6;
  const int g = lane >> 4, c = lane & 15;
  const int wm = w >> 1, wn = w & 1;
  const int m0 = blockIdx.y * 128, n0 = blockIdx.x * 128;

  f32x4 acc[4][4];
#pragma unroll
  for (int i = 0; i < 4; ++i)
#pragma unroll
    for (int j = 0; j < 4; ++j) acc[i][j] = (f32x4){0.f, 0.f, 0.f, 0.f};

  for (int k0 = 0; k0 < K; k0 += 32) {
    __syncthreads();
#pragma unroll
    for (int r = 0; r < 2; ++r) {
      int flat = r * 256 + tid;
      int row = flat >> 2, slot = flat & 3;
      int gsl = slot ^ (row & 3);                 // source-swizzle (rule #21)
      load_lds16(A + (size_t)(m0 + row) * K + k0 + gsl * 8,
                 &Atile[(r * 256 + w * 64) * 8]);
      load_lds16(Bt + (size_t)(n0 + row) * K + k0 + gsl * 8,
                 &Btile[(r * 256 + w * 64) * 8]);
    }
    __syncthreads();

    bf16x8 af[4], bfr[4];
#pragma unroll
    for (int mi = 0; mi < 4; ++mi) {
      int row = wm * 64 + mi * 16 + c;
      int sl = g ^ (row & 3);
      af[mi] = *(const bf16x8*)&Atile[row * 32 + sl * 8];
    }
#pragma unroll
    for (int ni = 0; ni < 4; ++ni) {
      int row = wn * 64 + ni * 16 + c;
      int sl = g ^ (row & 3);
      bfr[ni] = *(const bf16x8*)&Btile[row * 32 + sl * 8];
    }
#pragma unroll
    for (int mi = 0; mi < 4; ++mi)
#pragma unroll
      for (int ni = 0; ni < 4; ++ni)
        acc[mi][ni] = __builtin_amdgcn_mfma_f32_16x16x32_bf16(af[mi], bfr[ni],
                                                              acc[mi][ni], 0, 0, 0);
  }

#pragma unroll
  for (int mi = 0; mi < 4; ++mi)
#pragma unroll
    for (int ni = 0; ni < 4; ++ni) {
      int n = n0 + wn * 64 + ni * 16 + c;
#pragma unroll
      for (int j = 0; j < 4; ++j) {
        int m = m0 + wm * 64 + mi * 16 + g * 4 + j;
        float v = acc[mi][ni][j];
        if constexpr (EPI == 0) {
          int which = n >> 10, hn = n & 1023;
          int h = hn >> 6, d = hn & 63;
          int b = m >> 11, t = m & 2047;
          if (which == 0) v *= 0.18033688f;   // 1/sqrt(64) * log2(e) folded into Q
          O16[(size_t)which * PERQKV +
              (((size_t)(b * NHEAD + h) * T_LEN + t) * HDIM + d)] = f2bf(v);
        } else {
          O32[(size_t)m * N + n] = v;
        }
      }
    }
}

// ---- GEMM v3 (T4 counted-vmcnt): GEMM2 only (256 blocks = 1 round; ~15us) ----
template <int NB_TILES, int EPI>   // NB_TILES = N/256
__global__ __launch_bounds__(512, 2) void k_gemm3(const ushort_t* __restrict__ A,
                                                  const ushort_t* __restrict__ Bt,
                                                  ushort_t* __restrict__ O16,
                                                  float* __restrict__ O32) {
  __shared__ __align__(16) ushort_t As[3][128 * 64];   // 3 x 16KB
  __shared__ __align__(16) ushort_t Bs[3][256 * 64];   // 3 x 32KB
  const int tid = threadIdx.x, lane = tid & 63, w = tid >> 6;
  const int g = lane >> 4, c = lane & 15;
  const int wm = w & 1, wn = w >> 1;                   // 2M x 4N
  const int nblk = 64 * NB_TILES;
  const int chunk = nblk >> 3;                         // blocks per XCD
  const int bid = blockIdx.x;
  const int logical = (bid & 7) * chunk + (bid >> 3);  // T1 XCD swizzle
  const int mb = logical & 63, nb = logical >> 6;
  const int m0 = mb * 128, n0 = nb * 256;

  const int srow = lane >> 3, sgran = lane & 7;

  auto stage = [&](int t, int buf) {
    const int k0 = t * 64;
#pragma unroll
    for (int l = 0; l < 2; ++l) {
      int r = w * 16 + l * 8 + srow;
      load_lds16(A + (size_t)(m0 + r) * 1024 + k0 + ((sgran ^ (r & 7)) << 3),
                 &As[buf][(w * 16 + l * 8) * 64]);
    }
#pragma unroll
    for (int l = 0; l < 4; ++l) {
      int r = w * 32 + l * 8 + srow;
      load_lds16(Bt + (size_t)(n0 + r) * 1024 + k0 + ((sgran ^ (r & 7)) << 3),
                 &Bs[buf][(w * 32 + l * 8) * 64]);
    }
  };

  f32x4 acc[4][4];
#pragma unroll
  for (int i = 0; i < 4; ++i)
#pragma unroll
    for (int j = 0; j < 4; ++j) acc[i][j] = (f32x4){0.f, 0.f, 0.f, 0.f};

  stage(0, 0);
  stage(1, 1);

  for (int t = 0; t < 16; ++t) {
    if (t < 15) asm volatile("s_waitcnt vmcnt(6)" ::: "memory");
    else        asm volatile("s_waitcnt vmcnt(0)" ::: "memory");
    __builtin_amdgcn_s_barrier();
    __builtin_amdgcn_sched_barrier(0);

    if (t + 2 < 16) stage(t + 2, (t + 2) % 3);

    const int cur = t % 3;
    const ushort_t* abuf = &As[cur][0];
    const ushort_t* bbuf = &Bs[cur][0];
#pragma unroll
    for (int kk = 0; kk < 2; ++kk) {
      bf16x8 af[4], bq[4];
#pragma unroll
      for (int fr = 0; fr < 4; ++fr) {
        int r = wm * 64 + fr * 16 + c;
        af[fr] = *(const bf16x8*)&abuf[r * 64 + (((kk * 4 + g) ^ (r & 7)) << 3)];
      }
#pragma unroll
      for (int fc = 0; fc < 4; ++fc) {
        int r = wn * 64 + fc * 16 + c;
        bq[fc] = *(const bf16x8*)&bbuf[r * 64 + (((kk * 4 + g) ^ (r & 7)) << 3)];
      }
      __builtin_amdgcn_s_setprio(1);
#pragma unroll
      for (int fr = 0; fr < 4; ++fr)
#pragma unroll
        for (int fc = 0; fc < 4; ++fc)
          acc[fr][fc] = __builtin_amdgcn_mfma_f32_16x16x32_bf16(af[fr], bq[fc],
                                                                acc[fr][fc], 0, 0, 0);
      __builtin_amdgcn_s_setprio(0);
    }
  }

  // epilogue
#pragma unroll
  for (int fr = 0; fr < 4; ++fr)
#pragma unroll
    for (int fc = 0; fc < 4; ++fc) {
      int n = n0 + wn * 64 + fc * 16 + c;
#pragma unroll
      for (int j = 0; j < 4; ++j) {
        int m = m0 + wm * 64 + fr * 16 + g * 4 + j;
        float v = acc[fr][fc][j];
        if constexpr (EPI == 0) {
          int which = n >> 10, hn = n & 1023;
          int h = hn >> 6, d = hn & 63;
          int b = m >> 11, tt = m & 2047;
          if (which == 0) v *= 0.18033688f;
          O16[(size_t)which * PERQKV +
              (((size_t)(b * NHEAD + h) * T_LEN + tt) * HDIM + d)] = f2bf(v);
        } else {
          O32[(size_t)m * (64 * NB_TILES * 4) + n] = v;   // N = NB_TILES*256
        }
      }
    }
}

// ---------------- flash attention v11: v10 + stage_write overlapped with PV ----------------
// v10 (75.7us): MFMA ones-trick row sums, z16 C-in, raw exp2, permlane32_swap,
// v_perm V-pack, 4 uniform blocks/CU. v11: stage_write(next) issues BEFORE the
// PV MFMA cluster (other buffer -> no hazard; regs sourced last iter) so the
// 36 ds_writes overlap MFMA issue instead of serializing before the barrier.
__global__ __launch_bounds__(128, 2) void k_attn(const ushort_t* __restrict__ Q,
                                                 const ushort_t* __restrict__ Kv,
                                                 const ushort_t* __restrict__ Vv,
                                                 ushort_t* __restrict__ Y) {
  __shared__ __align__(16) ushort_t Kt[2][64 * 64];   // [k][d], granule swz ^(k&7)
  __shared__ __align__(16) ushort_t Vt[2][64 * 64];   // [d][k], granule swz ^(d&7)

  const int bid = blockIdx.x;                          // 0..1023
  const int bh = (bid & 7) * 8 + ((bid >> 3) & 7);     // 8 bh per XCD (L2-fit)
  const int pairidx = bid >> 6;                        // 0..15
  const int pA = 31 - pairidx, pB = pairidx;
  const int nktA = pA + 1;
  const int total = nktA + pB + 1;                     // 34 for every block

  const int tid = threadIdx.x, lane = tid & 63, w = tid >> 6;  // w in {0,1}
  const int hi = lane >> 5, lc = lane & 31;
  const size_t base = (size_t)bh * (T_LEN * HDIM);

  f32x16 z16;
#pragma unroll
  for (int i = 0; i < 16; ++i) z16[i] = 0.f;
  uint4v ow; ow[0] = ow[1] = ow[2] = ow[3] = 0x3F803F80u;   // 8x bf16 1.0
  const bf16x8 onesf = __builtin_bit_cast(bf16x8, ow);

  int q32 = pA * 64 + w * 32;
  bf16x8 qf[4];
#pragma unroll
  for (int st = 0; st < 4; ++st)
    qf[st] = *(const bf16x8*)(Q + base + (size_t)(q32 + lc) * HDIM + st * 16 + hi * 8);

  f32x16 o0, o1, ol;
#pragma unroll
  for (int i = 0; i < 16; ++i) { o0[i] = 0.f; o1[i] = 0.f; ol[i] = 0.f; }
  float mrun = 0.f;   // scores bounded ~7 << THR=11

  const int ksl = tid & 7, krow0 = tid >> 3;
  const int kpair = tid & 31, vk0 = 2 * kpair, vd0 = (tid >> 5) * 8;

  bf16x8 kreg[4];
  ushort8v vreg[4];
  auto stage_issue = [&](int kt) {
    const ushort_t* kb = Kv + base + (size_t)kt * 64 * HDIM;
    const ushort_t* vb = Vv + base + (size_t)kt * 64 * HDIM;
    vreg[0] = *(const ushort8v*)(vb + (size_t)vk0 * HDIM + vd0);
    vreg[1] = *(const ushort8v*)(vb + (size_t)(vk0 + 1) * HDIM + vd0);
    vreg[2] = *(const ushort8v*)(vb + (size_t)vk0 * HDIM + vd0 + 32);
    vreg[3] = *(const ushort8v*)(vb + (size_t)(vk0 + 1) * HDIM + vd0 + 32);
#pragma unroll
    for (int m = 0; m < 4; ++m)
      kreg[m] = *(const bf16x8*)(kb + (size_t)(krow0 + 16 * m) * HDIM + ksl * 8);
  };
  auto stage_write = [&](int buf) {
#pragma unroll
    for (int m = 0; m < 4; ++m) {
      int r = krow0 + 16 * m;
      *(bf16x8*)&Kt[buf][r * 64 + ((ksl ^ (r & 7)) << 3)] = kreg[m];
    }
    uint4v a0 = __builtin_bit_cast(uint4v, vreg[0]);
    uint4v a1 = __builtin_bit_cast(uint4v, vreg[1]);
    uint4v a2 = __builtin_bit_cast(uint4v, vreg[2]);
    uint4v a3 = __builtin_bit_cast(uint4v, vreg[3]);
#pragma unroll
    for (int i = 0; i < 4; ++i) {
      unsigned lo, hi2, lo2, hi3;
      asm("v_perm_b32 %0, %1, %2, %3" : "=v"(lo)  : "v"(a1[i]), "v"(a0[i]), "s"(0x05040100u));
      asm("v_perm_b32 %0, %1, %2, %3" : "=v"(hi2) : "v"(a1[i]), "v"(a0[i]), "s"(0x07060302u));
      asm("v_perm_b32 %0, %1, %2, %3" : "=v"(lo2) : "v"(a3[i]), "v"(a2[i]), "s"(0x05040100u));
      asm("v_perm_b32 %0, %1, %2, %3" : "=v"(hi3) : "v"(a3[i]), "v"(a2[i]), "s"(0x07060302u));
      int rd = vd0 + 2 * i;
      *(unsigned*)&Vt[buf][rd * 64 + (((kpair >> 2) ^ (rd & 7)) << 3) + 2 * (kpair & 3)] = lo;
      int rd1 = rd + 1;
      *(unsigned*)&Vt[buf][rd1 * 64 + (((kpair >> 2) ^ (rd1 & 7)) << 3) + 2 * (kpair & 3)] = hi2;
      int rd2 = rd + 32;
      *(unsigned*)&Vt[buf][rd2 * 64 + (((kpair >> 2) ^ (rd2 & 7)) << 3) + 2 * (kpair & 3)] = lo2;
      int rd3 = rd + 33;
      *(unsigned*)&Vt[buf][rd3 * 64 + (((kpair >> 2) ^ (rd3 & 7)) << 3) + 2 * (kpair & 3)] = hi3;
    }
  };

  const int b_ = bh >> 4, h_ = bh & 15;
  auto epilogue = [&]() {
#pragma unroll
    for (int r = 0; r < 16; ++r) {
      int cr = (r & 3) + 8 * (r >> 2) + 4 * hi;
      float iv = fast_rcp(ol[r]);
      size_t m = (size_t)b_ * T_LEN + q32 + cr;
      Y[m * D_DIM + h_ * HDIM + lc]      = f2bf(o0[r] * iv);
      Y[m * D_DIM + h_ * HDIM + 32 + lc] = f2bf(o1[r] * iv);
    }
  };

  stage_issue(0); stage_write(0);
  stage_issue(1);
  __syncthreads();

  for (int it = 0; it < total; ++it) {
    if (it == nktA) {
      epilogue();
      q32 = pB * 64 + w * 32;
#pragma unroll
      for (int st = 0; st < 4; ++st)
        qf[st] = *(const bf16x8*)(Q + base + (size_t)(q32 + lc) * HDIM + st * 16 + hi * 8);
#pragma unroll
      for (int i = 0; i < 16; ++i) { o0[i] = 0.f; o1[i] = 0.f; ol[i] = 0.f; }
      mrun = 0.f;
    }
    const int kt = (it < nktA) ? it : it - nktA;
    const int cur = it & 1;
    const ushort_t* kbuf = &Kt[cur][0];
    const ushort_t* vbuf = &Vt[cur][0];

    __builtin_amdgcn_s_setprio(1);
    bf16x8 kf0 = *(const bf16x8*)&kbuf[lc * 64 + ((hi ^ (lc & 7)) << 3)];
    f32x16 s0 = __builtin_amdgcn_mfma_f32_32x32x16_bf16(kf0, qf[0], z16, 0, 0, 0);
#pragma unroll
    for (int st = 1; st < 4; ++st) {
      bf16x8 kf = *(const bf16x8*)&kbuf[lc * 64 + (((2 * st + hi) ^ (lc & 7)) << 3)];
      s0 = __builtin_amdgcn_mfma_f32_32x32x16_bf16(kf, qf[st], s0, 0, 0, 0);
    }
    bf16x8 kg0 = *(const bf16x8*)&kbuf[(32 + lc) * 64 + ((hi ^ (lc & 7)) << 3)];
    f32x16 s1 = __builtin_amdgcn_mfma_f32_32x32x16_bf16(kg0, qf[0], z16, 0, 0, 0);
#pragma unroll
    for (int st = 1; st < 4; ++st) {
      bf16x8 kg = *(const bf16x8*)&kbuf[(32 + lc) * 64 + (((2 * st + hi) ^ (lc & 7)) << 3)];
      s1 = __builtin_amdgcn_mfma_f32_32x32x16_bf16(kg, qf[st], s1, 0, 0, 0);
    }
    __builtin_amdgcn_s_setprio(0);

    if (kt * 64 + 63 > q32) {
      const int q = q32 + lc;
#pragma unroll
      for (int r = 0; r < 16; ++r) {
        int cr = (r & 3) + 8 * (r >> 2) + 4 * hi;
        if (kt * 64 + cr > q)      s0[r] = -3.0e38f;
        if (kt * 64 + 32 + cr > q) s1[r] = -3.0e38f;
      }
    }

    float tm[8];
#pragma unroll
    for (int i = 0; i < 8; ++i) tm[i] = fmaxf(fmaxf(s0[i], s0[i + 8]), fmaxf(s1[i], s1[i + 8]));
#pragma unroll
    for (int i = 0; i < 4; ++i) tm[i] = fmaxf(tm[i], tm[i + 4]);
    float tmax = fmaxf(fmaxf(tm[0], tm[1]), fmaxf(tm[2], tm[3]));
    tmax = fmaxf(tmax, __shfl_xor(tmax, 32));

    if (!__all(tmax <= mrun + 11.0f)) {
      float mnew = fmaxf(mrun, tmax);
      float sc = fast_exp2(mrun - mnew);
      mrun = mnew;
#pragma unroll
      for (int r = 0; r < 16; ++r) {
        int cr = (r & 3) + 8 * (r >> 2) + 4 * hi;
        float scr = __shfl(sc, cr);
        o0[r] *= scr; o1[r] *= scr; ol[r] *= scr;
      }
    }

#pragma unroll
    for (int r = 0; r < 16; ++r) s0[r] = fast_exp2(s0[r] - mrun);
#pragma unroll
    for (int r = 0; r < 16; ++r) s1[r] = fast_exp2(s1[r] - mrun);

    unsigned wv[16];
#pragma unroll
    for (int i = 0; i < 8; ++i) {
      asm("v_cvt_pk_bf16_f32 %0, %1, %2" : "=v"(wv[i])     : "v"(s0[2 * i]), "v"(s0[2 * i + 1]));
      asm("v_cvt_pk_bf16_f32 %0, %1, %2" : "=v"(wv[8 + i]) : "v"(s1[2 * i]), "v"(s1[2 * i + 1]));
    }
    bf16x8 pf[4];
#pragma unroll
    for (int g4 = 0; g4 < 4; ++g4) {
      unsigned a0 = wv[4 * g4], a1 = wv[4 * g4 + 1];
      unsigned a2 = wv[4 * g4 + 2], a3 = wv[4 * g4 + 3];
      asm("v_permlane32_swap_b32 %0, %1" : "+v"(a0), "+v"(a2));
      asm("v_permlane32_swap_b32 %0, %1" : "+v"(a1), "+v"(a3));
      uint4v fw; fw[0] = a0; fw[1] = a1; fw[2] = a2; fw[3] = a3;
      pf[g4] = __builtin_bit_cast(bf16x8, fw);
    }

    // stage next tile's LDS writes BEFORE PV: they target the OTHER buffer and
    // overlap the MFMA cluster; the end-of-iter barrier orders them for it+1.
    if (it + 1 < total) stage_write((it + 1) & 1);

    __builtin_amdgcn_s_setprio(1);
#pragma unroll
    for (int km = 0; km < 4; ++km) {
      int gsl = ((2 * km + hi) ^ (lc & 7)) << 3;
      bf16x8 vb0 = *(const bf16x8*)&vbuf[lc * 64 + gsl];
      bf16x8 vb1 = *(const bf16x8*)&vbuf[(32 + lc) * 64 + gsl];
      o0 = __builtin_amdgcn_mfma_f32_32x32x16_bf16(pf[km], vb0, o0, 0, 0, 0);
      o1 = __builtin_amdgcn_mfma_f32_32x32x16_bf16(pf[km], vb1, o1, 0, 0, 0);
      ol = __builtin_amdgcn_mfma_f32_32x32x16_bf16(pf[km], onesf, ol, 0, 0, 0);
    }
    __builtin_amdgcn_s_setprio(0);

    if (it + 2 < total) {
      int itn = it + 2;
      stage_issue((itn < nktA) ? itn : itn - nktA);
    }
    __syncthreads();
  }

  epilogue();
}

extern "C" void kernel_launch(void* const* d_in, const int* in_sizes, int n_in,
                              void* d_out, int out_size, void* d_ws, size_t ws_size,
                              hipStream_t stream) {
  const float* x     = (const float*)d_in[0];
  const float* Wqkv  = (const float*)d_in[1];
  const float* Wproj = (const float*)d_in[2];
  float* out = (float*)d_out;
  ushort_t* ws = (ushort_t*)d_ws;

  ushort_t* Xb  = ws;
  ushort_t* WqT = Xb  + (size_t)MROWS * D_DIM;        // 8192*1024
  ushort_t* WpT = WqT + (size_t)3 * D_DIM * D_DIM;    // 3072*1024
  ushort_t* Qb  = WpT + (size_t)D_DIM * D_DIM;        // 1024*1024
  ushort_t* Kb  = Qb + PERQKV;
  ushort_t* Vb  = Kb + PERQKV;
  ushort_t* Yb  = Vb + PERQKV;

  k_prep<<<8192 + 4096, 256, 0, stream>>>(x, Wqkv, Wproj, Xb, WqT, WpT);
  k_gemm<3 * D_DIM, D_DIM, 0><<<dim3(3 * D_DIM / 128, MROWS / 128), 256, 0, stream>>>(Xb, WqT, Qb, nullptr);
  k_attn<<<1024, 128, 0, stream>>>(Qb, Kb, Vb, Yb);
  k_gemm3<4, 1><<<256, 512, 0, stream>>>(Yb, WpT, nullptr, out);
}